// Round 9
// baseline (119.027 us; speedup 1.0000x reference)
//
#include <hip/hip_runtime.h>
#include <hip/hip_bf16.h>
#include <math.h>

#define ALPHA 0.01f
#define MAXDEG 48

// ---------------------------------------------------------------------------
// Per-block frv recompute (32 threads): frv[l][p] = product of normalized
// rvec[l..2][p] (ETYPES=(0,2,4) -> rv only, no conjugates); frv[3]=1+0j.
// frvs layout: l*64 + p*2 + c.
// ---------------------------------------------------------------------------
__device__ __forceinline__ void compute_frv_block(const float* __restrict__ rvec,
                                                  float* __restrict__ frvs,
                                                  int tid) {
    if (tid < 32) {
        int p = tid;
        float fr = 1.f, fi = 0.f;
        frvs[3 * 64 + 2 * p]     = 1.f;
        frvs[3 * 64 + 2 * p + 1] = 0.f;
        for (int l = 2; l >= 0; --l) {
            float rr = rvec[l * 64 + 2 * p];
            float ri = rvec[l * 64 + 2 * p + 1];
            float inv = rsqrtf(rr * rr + ri * ri);
            rr *= inv; ri *= inv;
            float nr = fr * rr - fi * ri;
            float ni = fr * ri + fi * rr;
            fr = nr; fi = ni;
            frvs[l * 64 + 2 * p]     = fr;
            frvs[l * 64 + 2 * p + 1] = fi;
        }
    }
}

// ---------------------------------------------------------------------------
// prep: out0 + per-node logit tables.
//   q[n][0..7]   = feat[n]·w1[h]
//   q[n][8+l*8+h]= 0.25 * feat[n]·(rot_l^* w2[h])
// ONE node per thread (acc[10] float4 = 40 VGPRs; 2-node variant spilled).
// ---------------------------------------------------------------------------
__global__ void prep_kernel(const float* __restrict__ feat,
                            const float* __restrict__ w1,
                            const float* __restrict__ w2,
                            const float* __restrict__ rvec,
                            const int* __restrict__ ift,
                            float* __restrict__ out0,
                            float* __restrict__ q, int N) {
    __shared__ float frvs[256];
    __shared__ float wt[64 * 40];
    int tid = threadIdx.x;
    compute_frv_block(rvec, frvs, tid);
    __syncthreads();
    for (int i = tid; i < 512; i += 256) {          // w1 part
        int h = i >> 6, d = i & 63;
        wt[d * 40 + h] = w1[i];
    }
    for (int i = tid; i < 2048; i += 256) {         // rotated w2 part
        int l = i >> 9, r = i & 511, h = r >> 6, d = r & 63;
        float fr = frvs[l * 64 + (d & ~1)];
        float fi = frvs[l * 64 + (d | 1)];
        float sgn = (d & 1) ? -1.f : 1.f;
        float v = w2[h * 64 + d] * fr + sgn * w2[h * 64 + (d ^ 1)] * fi;
        wt[d * 40 + 8 + l * 8 + h] = 0.25f * v;
    }
    __syncthreads();

    int n = blockIdx.x * 256 + tid;
    if (n >= N) return;
    out0[n] = (float)ift[2 * (size_t)n];

    float4 acc[10];
#pragma unroll
    for (int k = 0; k < 10; ++k) acc[k] = make_float4(0.f, 0.f, 0.f, 0.f);
    const float4* row = (const float4*)(feat + (size_t)n * 64);
#pragma unroll
    for (int dd = 0; dd < 16; ++dd) {
        float4 x4 = row[dd];
        float cx[4] = {x4.x, x4.y, x4.z, x4.w};
#pragma unroll
        for (int c = 0; c < 4; ++c) {
            const float4* w4 = (const float4*)(wt + (dd * 4 + c) * 40);
            float x = cx[c];
#pragma unroll
            for (int k = 0; k < 10; ++k) {
                float4 w = w4[k];
                acc[k].x += x * w.x; acc[k].y += x * w.y;
                acc[k].z += x * w.z; acc[k].w += x * w.w;
            }
        }
    }
    float4* qo = (float4*)(q + (size_t)n * 40);
#pragma unroll
    for (int k = 0; k < 10; ++k) qo[k] = acc[k];
}

// ---------------------------------------------------------------------------
// edge: logits -> abuf (sequential, coalesced) + slot-list append.
// a[h] = leaky(q1[dst][h] + sum_l q2[src_l][l][h]).
// ---------------------------------------------------------------------------
__global__ void edge_kernel(const int* __restrict__ mp,
                            const float* __restrict__ q,
                            int* __restrict__ cnt,
                            int* __restrict__ slots,
                            float* __restrict__ abuf, int E) {
    int e = blockIdx.x * blockDim.x + threadIdx.x;
    if (e >= E) return;
    const int4 m4 = ((const int4*)mp)[e];
    const float4* qc = (const float4*)(q + (size_t)m4.w * 40);
    float4 a0 = qc[0], a1 = qc[1];
    int idx[4] = {m4.x, m4.y, m4.z, m4.w};
#pragma unroll
    for (int l = 0; l < 4; ++l) {
        const float4* ql = (const float4*)(q + (size_t)idx[l] * 40 + 8 + l * 8);
        float4 b0 = ql[0], b1 = ql[1];
        a0.x += b0.x; a0.y += b0.y; a0.z += b0.z; a0.w += b0.w;
        a1.x += b1.x; a1.y += b1.y; a1.z += b1.z; a1.w += b1.w;
    }
    a0.x = a0.x > 0.f ? a0.x : ALPHA * a0.x;
    a0.y = a0.y > 0.f ? a0.y : ALPHA * a0.y;
    a0.z = a0.z > 0.f ? a0.z : ALPHA * a0.z;
    a0.w = a0.w > 0.f ? a0.w : ALPHA * a0.w;
    a1.x = a1.x > 0.f ? a1.x : ALPHA * a1.x;
    a1.y = a1.y > 0.f ? a1.y : ALPHA * a1.y;
    a1.z = a1.z > 0.f ? a1.z : ALPHA * a1.z;
    a1.w = a1.w > 0.f ? a1.w : ALPHA * a1.w;
    float4* ao = (float4*)(abuf + (size_t)e * 8);
    ao[0] = a0; ao[1] = a1;
    int pos = atomicAdd(&cnt[m4.w], 1);
    if (pos < MAXDEG) slots[(size_t)m4.w * MAXDEG + pos] = e;
}

// ---------------------------------------------------------------------------
// node: one wave per node, SINGLE fused pass.
//  ft[n] = (sum_e exp(a_e)*hv_e) / (sum_e exp(a_e)) + 0.25*feat[n]
//  (no max-subtraction: logits bounded, exact in fp32; center leg uses
//   sum att = 1 and rot_3 = identity).
//  pair lanes: lane=(half,pair); float2 loads, complex mul in-lane.
//  att: 8 lanes/half exp() then 8 wave-broadcast shuffles; every lane
//  redundantly accumulates s8[h] so no denominator reduce pass is needed.
//  epilogue: stride-9 float2 LDS transpose, 2x float4 contiguous stores.
// ---------------------------------------------------------------------------
__global__ __launch_bounds__(256, 4)
void node_kernel(const float* __restrict__ feat,
                 const float* __restrict__ rvec,
                 const float* __restrict__ abuf,
                 const int* __restrict__ mp,
                 const int* __restrict__ cnt,
                 const int* __restrict__ slots,
                 float* __restrict__ ft, int N) {
    __shared__ float frvs[256];
    __shared__ float2 ftt2[4][32 * 9];
    int tid = threadIdx.x;
    compute_frv_block(rvec, frvs, tid);
    __syncthreads();

    int wid = (int)((blockIdx.x * blockDim.x + tid) >> 6);
    int lane = tid & 63;
    int w = tid >> 6;
    if (wid >= N) return;
    int deg = cnt[wid];
    if (deg > MAXDEG) deg = MAXDEG;
    const int* sl = slots + (size_t)wid * MAXDEG;

    int half = lane >> 5;          // which edge of the pair
    int pr   = lane & 31;          // complex pair index (d = 2*pr, 2*pr+1)
    float fr0[3], fi0[3];
#pragma unroll
    for (int l = 0; l < 3; ++l) {
        fr0[l] = frvs[l * 64 + pr * 2];
        fi0[l] = frvs[l * 64 + pr * 2 + 1];
    }
    float2 xc = *(const float2*)&feat[(size_t)wid * 64 + pr * 2];

    float2 acc[8];
    float s8[8];
#pragma unroll
    for (int hh = 0; hh < 8; ++hh) {
        acc[hh] = make_float2(0.f, 0.f);
        s8[hh] = 0.f;
    }

    for (int p = 0; p < deg; p += 4) {
#pragma unroll
        for (int s2 = 0; s2 < 2; ++s2) {
            int j = p + s2 * 2 + half;
            bool valid = j < deg;
            int jc = valid ? j : 0;
            int e = sl[jc];
            const int4 m4 = ((const int4*)mp)[e];
            // att: 8 lanes per half read + exp, then broadcast
            float ev = 0.f;
            if (pr < 8) {
                float av = abuf[(size_t)e * 8 + pr];
                ev = valid ? __expf(av) : 0.f;
            }
            float at[8];
#pragma unroll
            for (int hh = 0; hh < 8; ++hh) {
                at[hh] = __shfl(ev, half * 32 + hh);
                s8[hh] += at[hh];
            }
            int idx3[3] = {m4.x, m4.y, m4.z};
            float2 hv = make_float2(0.f, 0.f);
#pragma unroll
            for (int l = 0; l < 3; ++l) {
                float2 x = *(const float2*)&feat[(size_t)idx3[l] * 64 + pr * 2];
                hv.x += x.x * fr0[l] - x.y * fi0[l];
                hv.y += x.x * fi0[l] + x.y * fr0[l];
            }
            hv.x *= 0.25f;
            hv.y *= 0.25f;
#pragma unroll
            for (int hh = 0; hh < 8; ++hh) {
                acc[hh].x += at[hh] * hv.x;
                acc[hh].y += at[hh] * hv.y;
            }
        }
    }

    // cross-half reduce: both halves end with full segment sums
#pragma unroll
    for (int hh = 0; hh < 8; ++hh) {
        acc[hh].x += __shfl_xor(acc[hh].x, 32);
        acc[hh].y += __shfl_xor(acc[hh].y, 32);
        s8[hh]    += __shfl_xor(s8[hh], 32);
    }

    float cadd = (deg > 0) ? 0.25f : 0.f;   // empty segments output zeros
    if (half == 0) {
#pragma unroll
        for (int hh = 0; hh < 8; ++hh) {
            float r = (s8[hh] > 0.f) ? 1.f / s8[hh] : 0.f;
            float2 v;
            v.x = acc[hh].x * r + cadd * xc.x;
            v.y = acc[hh].y * r + cadd * xc.y;
            ftt2[w][pr * 9 + hh] = v;       // stride-9: conflict-free
        }
    }
    // same-wave LDS write->read
    float2 rr[4];
#pragma unroll
    for (int k2 = 0; k2 < 4; ++k2) {
        int f = lane * 4 + k2;
        rr[k2] = ftt2[w][(f & 31) * 9 + (f >> 5)];
    }
    float4 o0 = make_float4(rr[0].x, rr[0].y, rr[1].x, rr[1].y);
    float4 o1 = make_float4(rr[2].x, rr[2].y, rr[3].x, rr[3].y);
    float4* o = (float4*)(ft + (size_t)wid * 512 + lane * 8);
    o[0] = o0;
    o[1] = o1;
}

extern "C" void kernel_launch(void* const* d_in, const int* in_sizes, int n_in,
                              void* d_out, int out_size, void* d_ws, size_t ws_size,
                              hipStream_t stream) {
    const int*   mp   = (const int*)d_in[0];
    const int*   ift  = (const int*)d_in[1];
    const float* feat = (const float*)d_in[2];
    const float* rvec = (const float*)d_in[3];
    const float* w1   = (const float*)d_in[4];
    const float* w2   = (const float*)d_in[5];
    int E = in_sizes[0] / 4;
    int N = in_sizes[2] / 64;

    float* out0 = (float*)d_out;
    float* ft   = out0 + N;

    float* q     = (float*)d_ws;                           // N*40
    float* abuf  = q + (size_t)N * 40;                     // E*8
    int*   cnt   = (int*)(abuf + (size_t)E * 8);           // N
    int*   slots = cnt + N;                                // N*MAXDEG

    int nblkN = (N + 255) / 256;

    hipMemsetAsync(cnt, 0, (size_t)N * sizeof(int), stream);
    prep_kernel<<<nblkN, 256, 0, stream>>>(feat, w1, w2, rvec, ift,
                                           out0, q, N);
    edge_kernel<<<(E + 255) / 256, 256, 0, stream>>>(mp, q, cnt, slots,
                                                     abuf, E);
    node_kernel<<<(N + 3) / 4, 256, 0, stream>>>(feat, rvec, abuf, mp,
                                                 cnt, slots, ft, N);
}

// Round 10
// 110.158 us; speedup vs baseline: 1.0805x; 1.0805x over previous
//
#include <hip/hip_runtime.h>
#include <hip/hip_bf16.h>
#include <math.h>

#define ALPHA 0.01f
#define CAP 32

// ---------------------------------------------------------------------------
// Per-block frv recompute (32 threads): frv[l][p] = product of normalized
// rvec[l..2][p] (ETYPES=(0,2,4) -> rv only, no conjugates); frv[3]=1+0j.
// frvs layout: l*64 + p*2 + c.
// ---------------------------------------------------------------------------
__device__ __forceinline__ void compute_frv_block(const float* __restrict__ rvec,
                                                  float* __restrict__ frvs,
                                                  int tid) {
    if (tid < 32) {
        int p = tid;
        float fr = 1.f, fi = 0.f;
        frvs[3 * 64 + 2 * p]     = 1.f;
        frvs[3 * 64 + 2 * p + 1] = 0.f;
        for (int l = 2; l >= 0; --l) {
            float rr = rvec[l * 64 + 2 * p];
            float ri = rvec[l * 64 + 2 * p + 1];
            float inv = rsqrtf(rr * rr + ri * ri);
            rr *= inv; ri *= inv;
            float nr = fr * rr - fi * ri;
            float ni = fr * ri + fi * rr;
            fr = nr; fi = ni;
            frvs[l * 64 + 2 * p]     = fr;
            frvs[l * 64 + 2 * p + 1] = fi;
        }
    }
}

// ---------------------------------------------------------------------------
// prep: out0 + edge histogram (cnt pre-zeroed by memset; grid-strided over E
// before the early exit) + per-node logit tables.
//   q[n][0..7]   = feat[n]·w1[h]
//   q[n][8+l*8+h]= 0.25 * feat[n]·(rot_l^* w2[h])
// ONE node per thread (acc[10] float4 = 40 VGPRs; 2-node variant spilled).
// ---------------------------------------------------------------------------
__global__ void prep_kernel(const float* __restrict__ feat,
                            const float* __restrict__ w1,
                            const float* __restrict__ w2,
                            const float* __restrict__ rvec,
                            const int* __restrict__ ift,
                            const int* __restrict__ mp,
                            float* __restrict__ out0,
                            float* __restrict__ q,
                            int* __restrict__ cnt, int N, int E) {
    __shared__ float frvs[256];
    __shared__ float wt[64 * 40];
    int tid = threadIdx.x;
    compute_frv_block(rvec, frvs, tid);

    int gsz = gridDim.x * blockDim.x;
    for (int e = blockIdx.x * blockDim.x + tid; e < E; e += gsz)
        atomicAdd(&cnt[((const int4*)mp)[e].w], 1);

    __syncthreads();
    for (int i = tid; i < 512; i += 256) {          // w1 part
        int h = i >> 6, d = i & 63;
        wt[d * 40 + h] = w1[i];
    }
    for (int i = tid; i < 2048; i += 256) {         // rotated w2 part
        int l = i >> 9, r = i & 511, h = r >> 6, d = r & 63;
        float fr = frvs[l * 64 + (d & ~1)];
        float fi = frvs[l * 64 + (d | 1)];
        float sgn = (d & 1) ? -1.f : 1.f;
        float v = w2[h * 64 + d] * fr + sgn * w2[h * 64 + (d ^ 1)] * fi;
        wt[d * 40 + 8 + l * 8 + h] = 0.25f * v;
    }
    __syncthreads();

    int n = blockIdx.x * 256 + tid;
    if (n >= N) return;
    out0[n] = (float)ift[2 * (size_t)n];

    float4 acc[10];
#pragma unroll
    for (int k = 0; k < 10; ++k) acc[k] = make_float4(0.f, 0.f, 0.f, 0.f);
    const float4* row = (const float4*)(feat + (size_t)n * 64);
#pragma unroll
    for (int dd = 0; dd < 16; ++dd) {
        float4 x4 = row[dd];
        float cx[4] = {x4.x, x4.y, x4.z, x4.w};
#pragma unroll
        for (int c = 0; c < 4; ++c) {
            const float4* w4 = (const float4*)(wt + (dd * 4 + c) * 40);
            float x = cx[c];
#pragma unroll
            for (int k = 0; k < 10; ++k) {
                float4 w = w4[k];
                acc[k].x += x * w.x; acc[k].y += x * w.y;
                acc[k].z += x * w.z; acc[k].w += x * w.w;
            }
        }
    }
    float4* qo = (float4*)(q + (size_t)n * 40);
#pragma unroll
    for (int k = 0; k < 10; ++k) qo[k] = acc[k];
}

// ---------------------------------------------------------------------------
// scan1: per-256-block exclusive scan of cnt -> offL (block-local) + bsums.
// ---------------------------------------------------------------------------
__global__ void scan1_kernel(const int* __restrict__ cnt,
                             int* __restrict__ offL,
                             int* __restrict__ bsums, int N) {
    __shared__ int tmp[256];
    int tid = threadIdx.x;
    int gid = blockIdx.x * 256 + tid;
    int v = (gid < N) ? cnt[gid] : 0;
    tmp[tid] = v;
    __syncthreads();
#pragma unroll
    for (int ofs = 1; ofs < 256; ofs <<= 1) {
        int t = (tid >= ofs) ? tmp[tid - ofs] : 0;
        __syncthreads();
        tmp[tid] += t;
        __syncthreads();
    }
    if (gid < N) offL[gid] = tmp[tid] - v;         // exclusive, block-local
    if (tid == 255) bsums[blockIdx.x] = tmp[255];
}

// scan2: exclusive scan of block sums (B <= 256), single block.
__global__ void scan2_kernel(int* __restrict__ bsums, int B) {
    __shared__ int tmp[256];
    int tid = threadIdx.x;
    int v = (tid < B) ? bsums[tid] : 0;
    tmp[tid] = v;
    __syncthreads();
#pragma unroll
    for (int ofs = 1; ofs < 256; ofs <<= 1) {
        int t = (tid >= ofs) ? tmp[tid - ofs] : 0;
        __syncthreads();
        tmp[tid] += t;
        __syncthreads();
    }
    if (tid < B) bsums[tid] = tmp[tid] - v;        // exclusive block prefix
}

// ---------------------------------------------------------------------------
// edge_scatter: logits + CSR permute. Global offset computed on the fly
// (offL + bsums + per-dst cursor cur0, zero-initialized) — no scan3 pass.
// ---------------------------------------------------------------------------
__global__ void edge_scatter_kernel(const int* __restrict__ mp,
                                    const float* __restrict__ q,
                                    const int* __restrict__ offL,
                                    const int* __restrict__ bsums,
                                    int* __restrict__ cur0,
                                    int* __restrict__ mpperm,
                                    float* __restrict__ aperm, int E) {
    int e = blockIdx.x * blockDim.x + threadIdx.x;
    if (e >= E) return;
    const int4 m4 = ((const int4*)mp)[e];
    const float4* qc = (const float4*)(q + (size_t)m4.w * 40);
    float4 a0 = qc[0], a1 = qc[1];
    int idx[4] = {m4.x, m4.y, m4.z, m4.w};
#pragma unroll
    for (int l = 0; l < 4; ++l) {
        const float4* ql = (const float4*)(q + (size_t)idx[l] * 40 + 8 + l * 8);
        float4 b0 = ql[0], b1 = ql[1];
        a0.x += b0.x; a0.y += b0.y; a0.z += b0.z; a0.w += b0.w;
        a1.x += b1.x; a1.y += b1.y; a1.z += b1.z; a1.w += b1.w;
    }
    a0.x = a0.x > 0.f ? a0.x : ALPHA * a0.x;
    a0.y = a0.y > 0.f ? a0.y : ALPHA * a0.y;
    a0.z = a0.z > 0.f ? a0.z : ALPHA * a0.z;
    a0.w = a0.w > 0.f ? a0.w : ALPHA * a0.w;
    a1.x = a1.x > 0.f ? a1.x : ALPHA * a1.x;
    a1.y = a1.y > 0.f ? a1.y : ALPHA * a1.y;
    a1.z = a1.z > 0.f ? a1.z : ALPHA * a1.z;
    a1.w = a1.w > 0.f ? a1.w : ALPHA * a1.w;
    int dst = m4.w;
    int base = offL[dst] + bsums[dst >> 8];
    int pos = base + atomicAdd(&cur0[dst], 1);
    ((int4*)mpperm)[pos] = m4;
    float4* ap = (float4*)(aperm + (size_t)pos * 8);
    ap[0] = a0; ap[1] = a1;
}

// ---------------------------------------------------------------------------
// node: one wave per node, CSR reads.
//  Pass 1: expsum (no max; logits bounded -> exact in fp32) over coalesced
//          aperm, caching exp values in attc (LDS, stride-1 writes).
//  Pass 2: pair lanes (half,pair): float2 feat loads, complex mul in-lane,
//          l=3 leg replaced by 0.25*feat[wid] (rot_3=identity, sum att=1).
//          att via LDS broadcast (no shuffles in loop).
//  Epilogue: LDS transpose lds[d*9+h] — both write (16 banks, 2-way) and
//  read (32 banks, 2-way) conflict-free; 2x float4 contiguous stores.
// ---------------------------------------------------------------------------
__global__ void node_kernel(const float* __restrict__ feat,
                            const float* __restrict__ rvec,
                            const float* __restrict__ aperm,
                            const int* __restrict__ mpperm,
                            const int* __restrict__ offL,
                            const int* __restrict__ bsums,
                            const int* __restrict__ cnt,
                            float* __restrict__ ft, int N) {
    __shared__ float frvs[256];
    __shared__ float rs[4][8];
    __shared__ float attc[4][CAP][8];
    __shared__ float fto[4][576];      // [d*9 + h], 64*9 = 576
    int tid = threadIdx.x;
    compute_frv_block(rvec, frvs, tid);
    __syncthreads();

    int wid = (int)((blockIdx.x * blockDim.x + tid) >> 6);
    int lane = tid & 63;
    int w = tid >> 6;
    if (wid >= N) return;
    int beg = offL[wid] + bsums[wid >> 8];
    int deg = cnt[wid];
    int end = beg + deg;

    // ---- pass 1: expsum + attc cache; 64 lanes cover 8 edges/iter ----
    int h = lane & 7;
    float s = 0.f;
    {
        int j = lane >> 3;
        for (int idx = beg * 8 + lane; idx < end * 8; idx += 64, j += 8) {
            float ev = __expf(aperm[idx]);
            s += ev;
            if (j < CAP) attc[w][j][h] = ev;   // addr = j*8+h: stride-1
        }
    }
    s += __shfl_xor(s, 8);
    s += __shfl_xor(s, 16);
    s += __shfl_xor(s, 32);
    if (lane < 8) rs[w][lane] = (s > 0.f) ? 1.f / s : 0.f;
    // same-wave LDS write->read; compiler inserts lgkmcnt waits

    // ---- pass 2: pair-based aggregation ----
    int half = lane >> 5;          // which edge of the pair
    int pr   = lane & 31;          // complex pair index (d = 2*pr, 2*pr+1)
    float fr0[3], fi0[3];
#pragma unroll
    for (int l = 0; l < 3; ++l) {
        fr0[l] = frvs[l * 64 + pr * 2];
        fi0[l] = frvs[l * 64 + pr * 2 + 1];
    }
    float2 xc = *(const float2*)&feat[(size_t)wid * 64 + pr * 2];

    float2 acc[8];
#pragma unroll
    for (int hh = 0; hh < 8; ++hh) acc[hh] = make_float2(0.f, 0.f);

    for (int p = 0; p < deg; p += 4) {
#pragma unroll
        for (int s2 = 0; s2 < 2; ++s2) {
            int j = p + s2 * 2 + half;
            bool valid = j < deg;
            int jc = valid ? j : 0;
            const int4 m4 = ((const int4*)mpperm)[beg + jc];
            float at[8];
            if (jc < CAP) {
                float4 aa = *(const float4*)&attc[w][jc][0];   // broadcast
                float4 ab = *(const float4*)&attc[w][jc][4];
                at[0] = aa.x; at[1] = aa.y; at[2] = aa.z; at[3] = aa.w;
                at[4] = ab.x; at[5] = ab.y; at[6] = ab.z; at[7] = ab.w;
            } else {
                float4 aa = *(const float4*)&aperm[(size_t)(beg + jc) * 8];
                float4 ab = *(const float4*)&aperm[(size_t)(beg + jc) * 8 + 4];
                at[0] = __expf(aa.x); at[1] = __expf(aa.y);
                at[2] = __expf(aa.z); at[3] = __expf(aa.w);
                at[4] = __expf(ab.x); at[5] = __expf(ab.y);
                at[6] = __expf(ab.z); at[7] = __expf(ab.w);
            }
            if (!valid) {
#pragma unroll
                for (int hh = 0; hh < 8; ++hh) at[hh] = 0.f;
            }
            int idx3[3] = {m4.x, m4.y, m4.z};
            float2 hv = make_float2(0.f, 0.f);
#pragma unroll
            for (int l = 0; l < 3; ++l) {
                float2 x = *(const float2*)&feat[(size_t)idx3[l] * 64 + pr * 2];
                hv.x += x.x * fr0[l] - x.y * fi0[l];
                hv.y += x.x * fi0[l] + x.y * fr0[l];
            }
            hv.x *= 0.25f;
            hv.y *= 0.25f;
#pragma unroll
            for (int hh = 0; hh < 8; ++hh) {
                acc[hh].x += at[hh] * hv.x;
                acc[hh].y += at[hh] * hv.y;
            }
        }
    }

    // cross-half reduce: half 0 ends with the full segment sum
#pragma unroll
    for (int hh = 0; hh < 8; ++hh) {
        acc[hh].x += __shfl_xor(acc[hh].x, 32);
        acc[hh].y += __shfl_xor(acc[hh].y, 32);
    }

    float cadd = (deg > 0) ? 0.25f : 0.f;   // empty segments output zeros
    if (half == 0) {
#pragma unroll
        for (int hh = 0; hh < 8; ++hh) {
            float r = rs[w][hh];
            fto[w][(2 * pr) * 9 + hh]     = acc[hh].x * r + cadd * xc.x;
            fto[w][(2 * pr + 1) * 9 + hh] = acc[hh].y * r + cadd * xc.y;
        }
    }
    // same-wave LDS write->read
    float val[8];
#pragma unroll
    for (int k = 0; k < 8; ++k)
        val[k] = fto[w][((lane & 7) * 8 + k) * 9 + (lane >> 3)];
    float4 o0 = make_float4(val[0], val[1], val[2], val[3]);
    float4 o1 = make_float4(val[4], val[5], val[6], val[7]);
    float4* o = (float4*)(ft + (size_t)wid * 512 + lane * 8);
    o[0] = o0;
    o[1] = o1;
}

extern "C" void kernel_launch(void* const* d_in, const int* in_sizes, int n_in,
                              void* d_out, int out_size, void* d_ws, size_t ws_size,
                              hipStream_t stream) {
    const int*   mp   = (const int*)d_in[0];
    const int*   ift  = (const int*)d_in[1];
    const float* feat = (const float*)d_in[2];
    const float* rvec = (const float*)d_in[3];
    const float* w1   = (const float*)d_in[4];
    const float* w2   = (const float*)d_in[5];
    int E = in_sizes[0] / 4;
    int N = in_sizes[2] / 64;

    float* out0 = (float*)d_out;
    float* ft   = out0 + N;

    float* q      = (float*)d_ws;                          // N*40 floats
    float* aperm  = q + (size_t)N * 40;                    // E*8
    int*   mpperm = (int*)(aperm + (size_t)E * 8);         // E*4 (16B-aligned)
    int*   cnt    = mpperm + (size_t)E * 4;                // N
    int*   cur0   = cnt + N;                               // N (adjacent!)
    int*   offL   = cur0 + N;                              // N
    int*   bsums  = offL + N;                              // nblkN

    int nblkN = (N + 255) / 256;

    hipMemsetAsync(cnt, 0, (size_t)(2 * N) * sizeof(int), stream); // cnt+cur0
    prep_kernel<<<nblkN, 256, 0, stream>>>(feat, w1, w2, rvec, ift, mp,
                                           out0, q, cnt, N, E);
    scan1_kernel<<<nblkN, 256, 0, stream>>>(cnt, offL, bsums, N);
    scan2_kernel<<<1, 256, 0, stream>>>(bsums, nblkN);
    edge_scatter_kernel<<<(E + 255) / 256, 256, 0, stream>>>(mp, q, offL,
                                                             bsums, cur0,
                                                             mpperm, aperm, E);
    node_kernel<<<(N + 3) / 4, 256, 0, stream>>>(feat, rvec, aperm, mpperm,
                                                 offL, bsums, cnt, ft, N);
}

// Round 11
// 99.378 us; speedup vs baseline: 1.1977x; 1.1085x over previous
//
#include <hip/hip_runtime.h>
#include <hip/hip_bf16.h>
#include <math.h>

#define ALPHA 0.01f
#define CAP 32

// ---------------------------------------------------------------------------
// Per-block frv recompute (32 threads): frv[l][p] = product of normalized
// rvec[l..2][p] (ETYPES=(0,2,4) -> rv only, no conjugates); frv[3]=1+0j.
// frvs layout: l*64 + p*2 + c.
// ---------------------------------------------------------------------------
__device__ __forceinline__ void compute_frv_block(const float* __restrict__ rvec,
                                                  float* __restrict__ frvs,
                                                  int tid) {
    if (tid < 32) {
        int p = tid;
        float fr = 1.f, fi = 0.f;
        frvs[3 * 64 + 2 * p]     = 1.f;
        frvs[3 * 64 + 2 * p + 1] = 0.f;
        for (int l = 2; l >= 0; --l) {
            float rr = rvec[l * 64 + 2 * p];
            float ri = rvec[l * 64 + 2 * p + 1];
            float inv = rsqrtf(rr * rr + ri * ri);
            rr *= inv; ri *= inv;
            float nr = fr * rr - fi * ri;
            float ni = fr * ri + fi * rr;
            fr = nr; fi = ni;
            frvs[l * 64 + 2 * p]     = fr;
            frvs[l * 64 + 2 * p + 1] = fi;
        }
    }
}

// ---------------------------------------------------------------------------
// prep: out0 + edge histogram + per-node logit tables + frv export.
//   q[n][0..7]    = feat[n]·(w1[h] + 0.25*w2[h])      (w1 and l=3 identity leg)
//   q[n][8+l*8+h] = 0.25 * feat[n]·(rot_l^* w2[h]),  l=0..2
// Row = 32 floats = 128 B. ONE node per thread (acc[8] float4 = 32 VGPRs).
// ---------------------------------------------------------------------------
__global__ void prep_kernel(const float* __restrict__ feat,
                            const float* __restrict__ w1,
                            const float* __restrict__ w2,
                            const float* __restrict__ rvec,
                            const int* __restrict__ ift,
                            const int* __restrict__ mp,
                            float* __restrict__ out0,
                            float* __restrict__ q,
                            int* __restrict__ cnt,
                            float* __restrict__ frvg, int N, int E) {
    __shared__ float frvs[256];
    __shared__ float wt[64 * 32];
    int tid = threadIdx.x;
    compute_frv_block(rvec, frvs, tid);

    int gsz = gridDim.x * blockDim.x;
    for (int e = blockIdx.x * blockDim.x + tid; e < E; e += gsz)
        atomicAdd(&cnt[((const int4*)mp)[e].w], 1);

    __syncthreads();
    if (blockIdx.x == 0) frvg[tid] = frvs[tid];     // export for node
    for (int i = tid; i < 512; i += 256) {          // cols 0..7: w1 + 0.25*w2
        int h = i >> 6, d = i & 63;
        wt[d * 32 + h] = w1[i] + 0.25f * w2[i];
    }
    for (int i = tid; i < 1536; i += 256) {         // cols 8..31: rot w2, l<3
        int l = i >> 9, r = i & 511, h = r >> 6, d = r & 63;
        float fr = frvs[l * 64 + (d & ~1)];
        float fi = frvs[l * 64 + (d | 1)];
        float sgn = (d & 1) ? -1.f : 1.f;
        float v = w2[h * 64 + d] * fr + sgn * w2[h * 64 + (d ^ 1)] * fi;
        wt[d * 32 + 8 + l * 8 + h] = 0.25f * v;
    }
    __syncthreads();

    int n = blockIdx.x * 256 + tid;
    if (n >= N) return;
    out0[n] = (float)ift[2 * (size_t)n];

    float4 acc[8];
#pragma unroll
    for (int k = 0; k < 8; ++k) acc[k] = make_float4(0.f, 0.f, 0.f, 0.f);
    const float4* row = (const float4*)(feat + (size_t)n * 64);
#pragma unroll
    for (int dd = 0; dd < 16; ++dd) {
        float4 x4 = row[dd];
        float cx[4] = {x4.x, x4.y, x4.z, x4.w};
#pragma unroll
        for (int c = 0; c < 4; ++c) {
            const float4* w4 = (const float4*)(wt + (dd * 4 + c) * 32);
            float x = cx[c];
#pragma unroll
            for (int k = 0; k < 8; ++k) {
                float4 w = w4[k];
                acc[k].x += x * w.x; acc[k].y += x * w.y;
                acc[k].z += x * w.z; acc[k].w += x * w.w;
            }
        }
    }
    float4* qo = (float4*)(q + (size_t)n * 32);
#pragma unroll
    for (int k = 0; k < 8; ++k) qo[k] = acc[k];
}

// ---------------------------------------------------------------------------
// scan1: per-256-block exclusive scan of cnt -> offL (block-local) + bsums.
// ---------------------------------------------------------------------------
__global__ void scan1_kernel(const int* __restrict__ cnt,
                             int* __restrict__ offL,
                             int* __restrict__ bsums, int N) {
    __shared__ int tmp[256];
    int tid = threadIdx.x;
    int gid = blockIdx.x * 256 + tid;
    int v = (gid < N) ? cnt[gid] : 0;
    tmp[tid] = v;
    __syncthreads();
#pragma unroll
    for (int ofs = 1; ofs < 256; ofs <<= 1) {
        int t = (tid >= ofs) ? tmp[tid - ofs] : 0;
        __syncthreads();
        tmp[tid] += t;
        __syncthreads();
    }
    if (gid < N) offL[gid] = tmp[tid] - v;         // exclusive, block-local
    if (tid == 255) bsums[blockIdx.x] = tmp[255];
}

// scan2: exclusive scan of block sums (B <= 256), single block.
__global__ void scan2_kernel(int* __restrict__ bsums, int B) {
    __shared__ int tmp[256];
    int tid = threadIdx.x;
    int v = (tid < B) ? bsums[tid] : 0;
    tmp[tid] = v;
    __syncthreads();
#pragma unroll
    for (int ofs = 1; ofs < 256; ofs <<= 1) {
        int t = (tid >= ofs) ? tmp[tid - ofs] : 0;
        __syncthreads();
        tmp[tid] += t;
        __syncthreads();
    }
    if (tid < B) bsums[tid] = tmp[tid] - v;        // exclusive block prefix
}

// ---------------------------------------------------------------------------
// edge_scatter: logits + exp + CSR permute. aperm holds exp(leaky(a)).
// pos = offL[dst] + bsums[dst>>8] + cur0[dst]++  (no scan3 pass).
// ---------------------------------------------------------------------------
__global__ void edge_scatter_kernel(const int* __restrict__ mp,
                                    const float* __restrict__ q,
                                    const int* __restrict__ offL,
                                    const int* __restrict__ bsums,
                                    int* __restrict__ cur0,
                                    int* __restrict__ mpperm,
                                    float* __restrict__ aperm, int E) {
    int e = blockIdx.x * blockDim.x + threadIdx.x;
    if (e >= E) return;
    const int4 m4 = ((const int4*)mp)[e];
    const float4* qd = (const float4*)(q + (size_t)m4.w * 32);
    float4 a0 = qd[0], a1 = qd[1];
    int idx[3] = {m4.x, m4.y, m4.z};
#pragma unroll
    for (int l = 0; l < 3; ++l) {
        const float4* ql = (const float4*)(q + (size_t)idx[l] * 32 + 8 + l * 8);
        float4 b0 = ql[0], b1 = ql[1];
        a0.x += b0.x; a0.y += b0.y; a0.z += b0.z; a0.w += b0.w;
        a1.x += b1.x; a1.y += b1.y; a1.z += b1.z; a1.w += b1.w;
    }
    a0.x = __expf(a0.x > 0.f ? a0.x : ALPHA * a0.x);
    a0.y = __expf(a0.y > 0.f ? a0.y : ALPHA * a0.y);
    a0.z = __expf(a0.z > 0.f ? a0.z : ALPHA * a0.z);
    a0.w = __expf(a0.w > 0.f ? a0.w : ALPHA * a0.w);
    a1.x = __expf(a1.x > 0.f ? a1.x : ALPHA * a1.x);
    a1.y = __expf(a1.y > 0.f ? a1.y : ALPHA * a1.y);
    a1.z = __expf(a1.z > 0.f ? a1.z : ALPHA * a1.z);
    a1.w = __expf(a1.w > 0.f ? a1.w : ALPHA * a1.w);
    int dst = m4.w;
    int base = offL[dst] + bsums[dst >> 8];
    int pos = base + atomicAdd(&cur0[dst], 1);
    ((int4*)mpperm)[pos] = m4;
    float4* ap = (float4*)(aperm + (size_t)pos * 8);
    ap[0] = a0; ap[1] = a1;
}

// ---------------------------------------------------------------------------
// node: one wave per node, CSR reads. No block barrier (frv from global).
//  Prefetch: up to 8 edges' mpperm rows into regs (m4r[4]) BEFORE pass 1 so
//  their latency hides under the aperm sweep.
//  Pass 1: denominator = plain sum of aperm (already exp'd); attc LDS cache.
//  Pass 2: fully unrolled over the 4 register-resident edge pairs (12
//  independent feat gathers in flight); tail loop for deg>8.
//  Epilogue: conflict-free LDS transpose lds[d*9+h]; 2x float4 stores.
// ---------------------------------------------------------------------------
__global__ __launch_bounds__(256, 4)
void node_kernel(const float* __restrict__ feat,
                 const float* __restrict__ frvg,
                 const float* __restrict__ aperm,
                 const int* __restrict__ mpperm,
                 const int* __restrict__ offL,
                 const int* __restrict__ bsums,
                 const int* __restrict__ cnt,
                 float* __restrict__ ft, int N) {
    __shared__ float rs[4][8];
    __shared__ float attc[4][CAP][8];
    __shared__ float fto[4][576];      // [d*9 + h], 64*9 = 576
    int tid = threadIdx.x;
    int wid = (int)((blockIdx.x * blockDim.x + tid) >> 6);
    int lane = tid & 63;
    int w = tid >> 6;
    if (wid >= N) return;
    int beg = offL[wid] + bsums[wid >> 8];
    int deg = cnt[wid];
    int end = beg + deg;

    int half = lane >> 5;          // which edge of a pair
    int pr   = lane & 31;          // complex pair index (d = 2*pr, 2*pr+1)

    // ---- prefetch up to 8 edges' index rows into registers ----
    int bb = (deg > 0) ? beg : 0;
    int dm1 = (deg > 0) ? deg - 1 : 0;
    int4 m4r[4];
#pragma unroll
    for (int k = 0; k < 4; ++k) {
        int j = k * 2 + half;
        m4r[k] = ((const int4*)mpperm)[bb + min(j, dm1)];
    }

    // per-lane rotation constants from global (no barrier needed)
    float fr0[3], fi0[3];
#pragma unroll
    for (int l = 0; l < 3; ++l) {
        float2 f = ((const float2*)frvg)[l * 32 + pr];
        fr0[l] = f.x; fi0[l] = f.y;
    }
    float2 xc = *(const float2*)&feat[(size_t)wid * 64 + pr * 2];

    // ---- pass 1: denominator sum + attc cache (aperm already exp'd) ----
    int h = lane & 7;
    float s = 0.f;
    {
        int j = lane >> 3;
        for (int idx = beg * 8 + lane; idx < end * 8; idx += 64, j += 8) {
            float ev = aperm[idx];
            s += ev;
            if (j < CAP) attc[w][j][h] = ev;   // addr = j*8+h: stride-1
        }
    }
    s += __shfl_xor(s, 8);
    s += __shfl_xor(s, 16);
    s += __shfl_xor(s, 32);
    if (lane < 8) rs[w][lane] = (s > 0.f) ? 1.f / s : 0.f;
    // same-wave LDS write->read; compiler inserts lgkmcnt waits

    // ---- pass 2: main (edges 0..min(deg,8) from m4r), fully unrolled ----
    float2 acc[8];
#pragma unroll
    for (int hh = 0; hh < 8; ++hh) acc[hh] = make_float2(0.f, 0.f);

#pragma unroll
    for (int k = 0; k < 4; ++k) {
        int j = k * 2 + half;
        bool valid = j < deg;
        int jc = min(j, dm1);
        float4 aa = *(const float4*)&attc[w][jc][0];   // broadcast read
        float4 ab = *(const float4*)&attc[w][jc][4];
        float at[8] = {aa.x, aa.y, aa.z, aa.w, ab.x, ab.y, ab.z, ab.w};
        if (!valid) {
#pragma unroll
            for (int hh = 0; hh < 8; ++hh) at[hh] = 0.f;
        }
        int idx3[3] = {m4r[k].x, m4r[k].y, m4r[k].z};
        float2 hv = make_float2(0.f, 0.f);
#pragma unroll
        for (int l = 0; l < 3; ++l) {
            float2 x = *(const float2*)&feat[(size_t)idx3[l] * 64 + pr * 2];
            hv.x += x.x * fr0[l] - x.y * fi0[l];
            hv.y += x.x * fi0[l] + x.y * fr0[l];
        }
        hv.x *= 0.25f;
        hv.y *= 0.25f;
#pragma unroll
        for (int hh = 0; hh < 8; ++hh) {
            acc[hh].x += at[hh] * hv.x;
            acc[hh].y += at[hh] * hv.y;
        }
    }

    // ---- tail: deg > 8 (rare) ----
    for (int p = 8; p < deg; p += 2) {
        int j = p + half;
        bool valid = j < deg;
        int jc = valid ? j : deg - 1;
        const int4 m4 = ((const int4*)mpperm)[beg + jc];
        float at[8];
        if (jc < CAP) {
            float4 aa = *(const float4*)&attc[w][jc][0];
            float4 ab = *(const float4*)&attc[w][jc][4];
            at[0] = aa.x; at[1] = aa.y; at[2] = aa.z; at[3] = aa.w;
            at[4] = ab.x; at[5] = ab.y; at[6] = ab.z; at[7] = ab.w;
        } else {
            float4 aa = *(const float4*)&aperm[(size_t)(beg + jc) * 8];
            float4 ab = *(const float4*)&aperm[(size_t)(beg + jc) * 8 + 4];
            at[0] = aa.x; at[1] = aa.y; at[2] = aa.z; at[3] = aa.w;
            at[4] = ab.x; at[5] = ab.y; at[6] = ab.z; at[7] = ab.w;
        }
        if (!valid) {
#pragma unroll
            for (int hh = 0; hh < 8; ++hh) at[hh] = 0.f;
        }
        int idx3[3] = {m4.x, m4.y, m4.z};
        float2 hv = make_float2(0.f, 0.f);
#pragma unroll
        for (int l = 0; l < 3; ++l) {
            float2 x = *(const float2*)&feat[(size_t)idx3[l] * 64 + pr * 2];
            hv.x += x.x * fr0[l] - x.y * fi0[l];
            hv.y += x.x * fi0[l] + x.y * fr0[l];
        }
        hv.x *= 0.25f;
        hv.y *= 0.25f;
#pragma unroll
        for (int hh = 0; hh < 8; ++hh) {
            acc[hh].x += at[hh] * hv.x;
            acc[hh].y += at[hh] * hv.y;
        }
    }

    // cross-half reduce: half 0 ends with the full segment sum
#pragma unroll
    for (int hh = 0; hh < 8; ++hh) {
        acc[hh].x += __shfl_xor(acc[hh].x, 32);
        acc[hh].y += __shfl_xor(acc[hh].y, 32);
    }

    float cadd = (deg > 0) ? 0.25f : 0.f;   // empty segments output zeros
    if (half == 0) {
#pragma unroll
        for (int hh = 0; hh < 8; ++hh) {
            float r = rs[w][hh];
            fto[w][(2 * pr) * 9 + hh]     = acc[hh].x * r + cadd * xc.x;
            fto[w][(2 * pr + 1) * 9 + hh] = acc[hh].y * r + cadd * xc.y;
        }
    }
    // same-wave LDS write->read
    float val[8];
#pragma unroll
    for (int k = 0; k < 8; ++k)
        val[k] = fto[w][((lane & 7) * 8 + k) * 9 + (lane >> 3)];
    float4 o0 = make_float4(val[0], val[1], val[2], val[3]);
    float4 o1 = make_float4(val[4], val[5], val[6], val[7]);
    float4* o = (float4*)(ft + (size_t)wid * 512 + lane * 8);
    o[0] = o0;
    o[1] = o1;
}

extern "C" void kernel_launch(void* const* d_in, const int* in_sizes, int n_in,
                              void* d_out, int out_size, void* d_ws, size_t ws_size,
                              hipStream_t stream) {
    const int*   mp   = (const int*)d_in[0];
    const int*   ift  = (const int*)d_in[1];
    const float* feat = (const float*)d_in[2];
    const float* rvec = (const float*)d_in[3];
    const float* w1   = (const float*)d_in[4];
    const float* w2   = (const float*)d_in[5];
    int E = in_sizes[0] / 4;
    int N = in_sizes[2] / 64;

    float* out0 = (float*)d_out;
    float* ft   = out0 + N;

    float* q      = (float*)d_ws;                          // N*32 floats
    float* aperm  = q + (size_t)N * 32;                    // E*8
    int*   mpperm = (int*)(aperm + (size_t)E * 8);         // E*4 (16B-aligned)
    int*   cnt    = mpperm + (size_t)E * 4;                // N
    int*   cur0   = cnt + N;                               // N (adjacent!)
    int*   offL   = cur0 + N;                              // N
    int*   bsums  = offL + N;                              // nblkN
    float* frvg   = (float*)(bsums + ((N + 255) / 256));   // 256 floats

    int nblkN = (N + 255) / 256;

    hipMemsetAsync(cnt, 0, (size_t)(2 * N) * sizeof(int), stream); // cnt+cur0
    prep_kernel<<<nblkN, 256, 0, stream>>>(feat, w1, w2, rvec, ift, mp,
                                           out0, q, cnt, frvg, N, E);
    scan1_kernel<<<nblkN, 256, 0, stream>>>(cnt, offL, bsums, N);
    scan2_kernel<<<1, 256, 0, stream>>>(bsums, nblkN);
    edge_scatter_kernel<<<(E + 255) / 256, 256, 0, stream>>>(mp, q, offL,
                                                             bsums, cur0,
                                                             mpperm, aperm, E);
    node_kernel<<<(N + 3) / 4, 256, 0, stream>>>(feat, frvg, aperm, mpperm,
                                                 offL, bsums, cnt, ft, N);
}